// Round 14
// baseline (142.257 us; speedup 1.0000x reference)
//
#include <hip/hip_runtime.h>

#define BN 8192      // B*N
#define NP 1024      // N
#define NF 64        // F_OUT
#define NSEG 8192
#define CAP 256      // bucket capacity; overflow handled exactly
#define NB 256       // counting blocks
#define EPB 4096     // edges per counting block
#define OVF_MAX 4096

typedef float f32x4 __attribute__((ext_vector_type(4)));
typedef unsigned long long ull;

// K1: blocks [0,NB) build per-block seg histograms in LDS -> counts[b][*]
//     blocks [NB,..) dual MLP (wave per row, shfl broadcast); 512 thr = 8 rows/block
__global__ __launch_bounds__(512) void count_kernel(
    const float* __restrict__ x,
    const float* __restrict__ W1, const float* __restrict__ b1,
    const float* __restrict__ W2, const float* __restrict__ b2,
    const float* __restrict__ Ws1, const float* __restrict__ bs1,
    const float* __restrict__ Ws2, const float* __restrict__ bs2,
    const int* __restrict__ eb, const int* __restrict__ ei,
    int* __restrict__ counts,
    float* __restrict__ x1, float* __restrict__ out, int nnz)
{
    __shared__ int hist[NSEG];
    if ((int)blockIdx.x < NB) {
        const int t = threadIdx.x;
        #pragma unroll
        for (int q = 0; q < 4; ++q)
            *(int4*)(hist + (q * 512 + t) * 4) = make_int4(0, 0, 0, 0);
        __syncthreads();
        const int base = blockIdx.x * EPB;
        #pragma unroll
        for (int q = 0; q < 2; ++q) {
            const int e0 = base + (q * 512 + t) * 4;
            if (e0 < nnz) {
                const int4 b4 = *(const int4*)(eb + e0);
                const int4 i4 = *(const int4*)(ei + e0);
                atomicAdd(&hist[b4.x * NP + i4.x], 1);
                atomicAdd(&hist[b4.y * NP + i4.y], 1);
                atomicAdd(&hist[b4.z * NP + i4.z], 1);
                atomicAdd(&hist[b4.w * NP + i4.w], 1);
            }
        }
        __syncthreads();
        int* row = counts + (size_t)blockIdx.x * NSEG;
        #pragma unroll
        for (int q = 0; q < 4; ++q) {
            const int idx = (q * 512 + t) * 4;
            *(int4*)(row + idx) = *(const int4*)(hist + idx);
        }
    } else {
        // dual MLP: one wave per row, shfl broadcasts, no barriers
        const int row = ((int)blockIdx.x - NB) * 8 + (threadIdx.x >> 6);
        const int t = threadIdx.x & 63;
        const float xv = x[(size_t)row * NF + t];
        float a1 = b1[t], a2 = bs1[t];
        #pragma unroll 8
        for (int c = 0; c < NF; ++c) {
            const float xc = __shfl(xv, c);
            a1 = fmaf(xc, W1[c * NF + t], a1);
            a2 = fmaf(xc, Ws1[c * NF + t], a2);
        }
        const float h1 = fmaxf(a1, 0.f), h2 = fmaxf(a2, 0.f);
        float o1 = b2[t], o2 = bs2[t];
        #pragma unroll 8
        for (int c = 0; c < NF; ++c) {
            o1 = fmaf(__shfl(h1, c), W2[c * NF + t], o1);
            o2 = fmaf(__shfl(h2, c), Ws2[c * NF + t], o2);
        }
        x1[(size_t)row * NF + t]  = fmaxf(o1, 0.f);
        out[(size_t)row * NF + t] = fmaxf(o2, 0.f);
    }
}

// K2: per-seg exclusive scan across the 256 block rows (fully coalesced).
__global__ __launch_bounds__(256) void scan_kernel(
    const int* __restrict__ counts,
    int* __restrict__ offs, int* __restrict__ deg, int* __restrict__ ovf_cnt)
{
    const int s = blockIdx.x * 256 + threadIdx.x;   // 8192 threads total
    int run = 0;
    #pragma unroll 16
    for (int b = 0; b < NB; ++b) {
        const int v = counts[(size_t)b * NSEG + s];
        offs[(size_t)b * NSEG + s] = run;
        run += v;
    }
    deg[s] = run;
    if (s == 0) *ovf_cnt = 0;
}

// K3: deterministic scatter, 512 threads (8 waves/CU). LDS cursor row;
// rec writes are nontemporal 8 B stores (no read-for-ownership).
__global__ __launch_bounds__(512) void scatter_kernel(
    const int* __restrict__ eb, const int* __restrict__ ei,
    const int* __restrict__ ej, const int* __restrict__ ek,
    const int* __restrict__ offs,
    int2* __restrict__ rec, int* __restrict__ ovf_cnt, int4* __restrict__ ovf,
    int nnz)
{
    __shared__ int cur[NSEG];
    const int t = threadIdx.x;
    const int* row = offs + (size_t)blockIdx.x * NSEG;
    #pragma unroll
    for (int q = 0; q < 4; ++q) {
        const int idx = (q * 512 + t) * 4;
        *(int4*)(cur + idx) = *(const int4*)(row + idx);
    }
    __syncthreads();
    const int base = blockIdx.x * EPB;
    #pragma unroll
    for (int q = 0; q < 2; ++q) {
        const int e0 = base + (q * 512 + t) * 4;
        if (e0 < nnz) {
            const int4 b4 = *(const int4*)(eb + e0);
            const int4 i4 = *(const int4*)(ei + e0);
            const int4 j4 = *(const int4*)(ej + e0);
            const int4 k4 = *(const int4*)(ek + e0);
            const int segs[4] = {b4.x * NP + i4.x, b4.y * NP + i4.y,
                                 b4.z * NP + i4.z, b4.w * NP + i4.w};
            const int jks[4]  = {(j4.x << 10) | k4.x, (j4.y << 10) | k4.y,
                                 (j4.z << 10) | k4.z, (j4.w << 10) | k4.w};
            #pragma unroll
            for (int c = 0; c < 4; ++c) {
                const int pos = atomicAdd(&cur[segs[c]], 1);   // LDS atomic
                if (pos < CAP) {
                    const ull v = ((ull)(unsigned)jks[c] << 32) | (unsigned)(e0 + c);
                    __builtin_nontemporal_store(
                        v, (ull*)(rec + (size_t)segs[c] * CAP + pos));
                } else {
                    const int o = atomicAdd(ovf_cnt, 1);
                    if (o < OVF_MAX) ovf[o] = make_int4(segs[c], e0 + c, jks[c], 0);
                }
            }
        }
    }
}

// Wave-per-segment gather: 4 independent waves per block, NO barriers.
// (Byte-identical structure to round 13.)
__global__ __launch_bounds__(256, 8) void gather_kernel(
    const f32x4* __restrict__ Wv4, const f32x4* __restrict__ x14,
    const int* __restrict__ deg, const int2* __restrict__ rec,
    const int* __restrict__ ovf_cnt, const int4* __restrict__ ovf,
    f32x4* __restrict__ out4)
{
    __shared__ int2 srec[4][CAP + 4];
    const int w    = threadIdx.x >> 6;
    const int lane = threadIdx.x & 63;
    const int seg  = blockIdx.x * 4 + w;
    const int b    = seg >> 10;
    const int dtrue = deg[seg];
    const int cnt  = min(dtrue, CAP);
    const int cnt4 = (cnt + 3) & ~3;

    for (int i = lane; i < cnt; i += 64)
        srec[w][i] = rec[(size_t)seg * CAP + i];
    if (lane < cnt4 - cnt)
        srec[w][cnt + lane] = make_int2(0, 0);

    const int sub = lane >> 4;
    const int c16 = lane & 15;
    const f32x4* __restrict__ x1b = x14 + ((size_t)b << 10) * 16;

    f32x4 acc = {0.f, 0.f, 0.f, 0.f};
    #pragma unroll 2
    for (int it = 0; it < cnt4; it += 4) {
        const int idx = it + sub;
        const float m = (idx < cnt) ? 1.f : 0.f;
        const int2 r = srec[w][idx];
        const int j = (r.y >> 10) & 1023, k = r.y & 1023;
        const f32x4 wv = __builtin_nontemporal_load(Wv4 + (size_t)(unsigned)r.x * 16 + c16);
        const f32x4 xj = x1b[j * 16 + c16];
        const f32x4 xk = x1b[k * 16 + c16];
        acc += (m * wv) * (xj * xk);
    }

    const int novf = min(ovf_cnt[0], OVF_MAX);
    if (novf > 0) {
        for (int o = 0; o < novf; ++o) {
            const int4 r = ovf[o];
            if (r.x == seg) {
                const float m = (sub == 0) ? 1.f : 0.f;
                const int j = (r.z >> 10) & 1023, k = r.z & 1023;
                const f32x4 wv = Wv4[(size_t)(unsigned)r.y * 16 + c16];
                acc += (m * wv) * (x1b[j * 16 + c16] * x1b[k * 16 + c16]);
            }
        }
    }

    #pragma unroll
    for (int mm = 16; mm < 64; mm <<= 1) {
        acc.x += __shfl_xor(acc.x, mm);
        acc.y += __shfl_xor(acc.y, mm);
        acc.z += __shfl_xor(acc.z, mm);
        acc.w += __shfl_xor(acc.w, mm);
    }

    if (sub == 0) {
        const float a = 1.0f / ((float)dtrue + 1e-10f);
        f32x4 o = out4[(size_t)seg * 16 + c16];
        out4[(size_t)seg * 16 + c16] = o + a * acc;
    }
}

extern "C" void kernel_launch(void* const* d_in, const int* in_sizes, int n_in,
                              void* d_out, int out_size, void* d_ws, size_t ws_size,
                              hipStream_t stream) {
    const float* x   = (const float*)d_in[0];
    const float* Wv  = (const float*)d_in[1];
    const int*   eb  = (const int*)d_in[2];
    const int*   ei  = (const int*)d_in[3];
    const int*   ej  = (const int*)d_in[4];
    const int*   ek  = (const int*)d_in[5];
    const float* W1  = (const float*)d_in[6];
    const float* b1  = (const float*)d_in[7];
    const float* W2  = (const float*)d_in[8];
    const float* b2  = (const float*)d_in[9];
    const float* Ws1 = (const float*)d_in[10];
    const float* bs1 = (const float*)d_in[11];
    const float* Ws2 = (const float*)d_in[12];
    const float* bs2 = (const float*)d_in[13];
    float* out = (float*)d_out;
    const int nnz = in_sizes[2];

    char* ws = (char*)d_ws;
    float* x1    = (float*)ws;                             // [0, 2MB)
    int* deg     = (int*)(ws + (2 << 20));                 // 32 KB
    int* ovf_cnt = (int*)(ws + (2 << 20) + (32 << 10));    // 4 B
    int4* ovf    = (int4*)(ws + (2 << 20) + (64 << 10));   // 64 KB
    int* counts  = (int*)(ws + (4 << 20));                 // [4MB, 12MB)
    int* offs    = (int*)(ws + (12 << 20));                // [12MB, 20MB)
    int2* rec    = (int2*)(ws + (20 << 20));               // [20MB, 36MB)

    count_kernel<<<NB + BN / 8, 512, 0, stream>>>(x, W1, b1, W2, b2, Ws1, bs1, Ws2, bs2,
                                                  eb, ei, counts, x1, out, nnz);
    scan_kernel<<<NSEG / 256, 256, 0, stream>>>(counts, offs, deg, ovf_cnt);
    scatter_kernel<<<NB, 512, 0, stream>>>(eb, ei, ej, ek, offs, rec, ovf_cnt, ovf, nnz);
    gather_kernel<<<NSEG / 4, 256, 0, stream>>>((const f32x4*)Wv, (const f32x4*)x1,
                                                deg, rec, ovf_cnt, ovf, (f32x4*)out);
}

// Round 15
// 134.714 us; speedup vs baseline: 1.0560x; 1.0560x over previous
//
#include <hip/hip_runtime.h>

#define BN 8192      // B*N
#define NP 1024      // N
#define NF 64        // F_OUT
#define NSEG 8192
#define CAP 256      // bucket capacity; overflow handled exactly
#define NB 256       // counting blocks
#define EPB 4096     // edges per counting block
#define OVF_MAX 4096

typedef float f32x4 __attribute__((ext_vector_type(4)));

// K1: blocks [0,NB) build per-block seg histograms in LDS -> counts[b][*]
//     blocks [NB,..) dual MLP (wave per row, shfl broadcast)
__global__ __launch_bounds__(256) void count_kernel(
    const float* __restrict__ x,
    const float* __restrict__ W1, const float* __restrict__ b1,
    const float* __restrict__ W2, const float* __restrict__ b2,
    const float* __restrict__ Ws1, const float* __restrict__ bs1,
    const float* __restrict__ Ws2, const float* __restrict__ bs2,
    const int* __restrict__ eb, const int* __restrict__ ei,
    int* __restrict__ counts,
    float* __restrict__ x1, float* __restrict__ out, int nnz)
{
    __shared__ int hist[NSEG];
    if ((int)blockIdx.x < NB) {
        const int t = threadIdx.x;
        #pragma unroll
        for (int q = 0; q < 8; ++q)
            *(int4*)(hist + (q * 256 + t) * 4) = make_int4(0, 0, 0, 0);
        __syncthreads();
        const int base = blockIdx.x * EPB;
        #pragma unroll
        for (int q = 0; q < 4; ++q) {
            const int e0 = base + q * 1024 + t * 4;
            if (e0 < nnz) {
                const int4 b4 = *(const int4*)(eb + e0);
                const int4 i4 = *(const int4*)(ei + e0);
                atomicAdd(&hist[b4.x * NP + i4.x], 1);
                atomicAdd(&hist[b4.y * NP + i4.y], 1);
                atomicAdd(&hist[b4.z * NP + i4.z], 1);
                atomicAdd(&hist[b4.w * NP + i4.w], 1);
            }
        }
        __syncthreads();
        int* row = counts + (size_t)blockIdx.x * NSEG;
        #pragma unroll
        for (int q = 0; q < 8; ++q) {
            const int idx = (q * 256 + t) * 4;
            *(int4*)(row + idx) = *(const int4*)(hist + idx);
        }
    } else {
        // dual MLP: one wave per row, shfl broadcasts, no barriers
        const int row = ((int)blockIdx.x - NB) * 4 + (threadIdx.x >> 6);
        const int t = threadIdx.x & 63;
        const float xv = x[(size_t)row * NF + t];
        float a1 = b1[t], a2 = bs1[t];
        #pragma unroll 8
        for (int c = 0; c < NF; ++c) {
            const float xc = __shfl(xv, c);
            a1 = fmaf(xc, W1[c * NF + t], a1);
            a2 = fmaf(xc, Ws1[c * NF + t], a2);
        }
        const float h1 = fmaxf(a1, 0.f), h2 = fmaxf(a2, 0.f);
        float o1 = b2[t], o2 = bs2[t];
        #pragma unroll 8
        for (int c = 0; c < NF; ++c) {
            o1 = fmaf(__shfl(h1, c), W2[c * NF + t], o1);
            o2 = fmaf(__shfl(h2, c), Ws2[c * NF + t], o2);
        }
        x1[(size_t)row * NF + t]  = fmaxf(o1, 0.f);
        out[(size_t)row * NF + t] = fmaxf(o2, 0.f);
    }
}

// K2: per-seg exclusive scan across the 256 block rows (fully coalesced).
__global__ __launch_bounds__(256) void scan_kernel(
    const int* __restrict__ counts,
    int* __restrict__ offs, int* __restrict__ deg, int* __restrict__ ovf_cnt)
{
    const int s = blockIdx.x * 256 + threadIdx.x;   // 8192 threads total
    int run = 0;
    #pragma unroll 16
    for (int b = 0; b < NB; ++b) {
        const int v = counts[(size_t)b * NSEG + s];
        offs[(size_t)b * NSEG + s] = run;
        run += v;
    }
    deg[s] = run;
    if (s == 0) *ovf_cnt = 0;
}

// K3: deterministic scatter. Block's cursor row lives in LDS (atomics are LDS-local);
// global rec position = offs[b][seg] + local append index. No global atomics.
__global__ __launch_bounds__(256) void scatter_kernel(
    const int* __restrict__ eb, const int* __restrict__ ei,
    const int* __restrict__ ej, const int* __restrict__ ek,
    const int* __restrict__ offs,
    int2* __restrict__ rec, int* __restrict__ ovf_cnt, int4* __restrict__ ovf,
    int nnz)
{
    __shared__ int cur[NSEG];
    const int t = threadIdx.x;
    const int* row = offs + (size_t)blockIdx.x * NSEG;
    #pragma unroll
    for (int q = 0; q < 8; ++q) {
        const int idx = (q * 256 + t) * 4;
        *(int4*)(cur + idx) = *(const int4*)(row + idx);
    }
    __syncthreads();
    const int base = blockIdx.x * EPB;
    #pragma unroll
    for (int q = 0; q < 4; ++q) {
        const int e0 = base + q * 1024 + t * 4;
        if (e0 < nnz) {
            const int4 b4 = *(const int4*)(eb + e0);
            const int4 i4 = *(const int4*)(ei + e0);
            const int4 j4 = *(const int4*)(ej + e0);
            const int4 k4 = *(const int4*)(ek + e0);
            const int segs[4] = {b4.x * NP + i4.x, b4.y * NP + i4.y,
                                 b4.z * NP + i4.z, b4.w * NP + i4.w};
            const int jks[4]  = {(j4.x << 10) | k4.x, (j4.y << 10) | k4.y,
                                 (j4.z << 10) | k4.z, (j4.w << 10) | k4.w};
            #pragma unroll
            for (int c = 0; c < 4; ++c) {
                const int pos = atomicAdd(&cur[segs[c]], 1);   // LDS atomic
                if (pos < CAP) {
                    rec[(size_t)segs[c] * CAP + pos] = make_int2(e0 + c, jks[c]);
                } else {
                    const int o = atomicAdd(ovf_cnt, 1);
                    if (o < OVF_MAX) ovf[o] = make_int4(segs[c], e0 + c, jks[c], 0);
                }
            }
        }
    }
}

// Wave-per-segment gather: 4 independent waves per block, NO barriers.
// R13 structure; ONLY change: Wv load is a plain (cacheable) load so Wv can
// stay L3-resident across graph replays (Infinity Cache = 256 MB = |Wv|).
__global__ __launch_bounds__(256, 8) void gather_kernel(
    const f32x4* __restrict__ Wv4, const f32x4* __restrict__ x14,
    const int* __restrict__ deg, const int2* __restrict__ rec,
    const int* __restrict__ ovf_cnt, const int4* __restrict__ ovf,
    f32x4* __restrict__ out4)
{
    __shared__ int2 srec[4][CAP + 4];
    const int w    = threadIdx.x >> 6;
    const int lane = threadIdx.x & 63;
    const int seg  = blockIdx.x * 4 + w;
    const int b    = seg >> 10;
    const int dtrue = deg[seg];
    const int cnt  = min(dtrue, CAP);
    const int cnt4 = (cnt + 3) & ~3;

    for (int i = lane; i < cnt; i += 64)
        srec[w][i] = rec[(size_t)seg * CAP + i];
    if (lane < cnt4 - cnt)
        srec[w][cnt + lane] = make_int2(0, 0);

    const int sub = lane >> 4;
    const int c16 = lane & 15;
    const f32x4* __restrict__ x1b = x14 + ((size_t)b << 10) * 16;

    f32x4 acc = {0.f, 0.f, 0.f, 0.f};
    #pragma unroll 2
    for (int it = 0; it < cnt4; it += 4) {
        const int idx = it + sub;
        const float m = (idx < cnt) ? 1.f : 0.f;
        const int2 r = srec[w][idx];
        const int j = (r.y >> 10) & 1023, k = r.y & 1023;
        const f32x4 wv = Wv4[(size_t)(unsigned)r.x * 16 + c16];   // cacheable
        const f32x4 xj = x1b[j * 16 + c16];
        const f32x4 xk = x1b[k * 16 + c16];
        acc += (m * wv) * (xj * xk);
    }

    const int novf = min(ovf_cnt[0], OVF_MAX);
    if (novf > 0) {
        for (int o = 0; o < novf; ++o) {
            const int4 r = ovf[o];
            if (r.x == seg) {
                const float m = (sub == 0) ? 1.f : 0.f;
                const int j = (r.z >> 10) & 1023, k = r.z & 1023;
                const f32x4 wv = Wv4[(size_t)(unsigned)r.y * 16 + c16];
                acc += (m * wv) * (x1b[j * 16 + c16] * x1b[k * 16 + c16]);
            }
        }
    }

    #pragma unroll
    for (int mm = 16; mm < 64; mm <<= 1) {
        acc.x += __shfl_xor(acc.x, mm);
        acc.y += __shfl_xor(acc.y, mm);
        acc.z += __shfl_xor(acc.z, mm);
        acc.w += __shfl_xor(acc.w, mm);
    }

    if (sub == 0) {
        const float a = 1.0f / ((float)dtrue + 1e-10f);
        f32x4 o = out4[(size_t)seg * 16 + c16];
        out4[(size_t)seg * 16 + c16] = o + a * acc;
    }
}

extern "C" void kernel_launch(void* const* d_in, const int* in_sizes, int n_in,
                              void* d_out, int out_size, void* d_ws, size_t ws_size,
                              hipStream_t stream) {
    const float* x   = (const float*)d_in[0];
    const float* Wv  = (const float*)d_in[1];
    const int*   eb  = (const int*)d_in[2];
    const int*   ei  = (const int*)d_in[3];
    const int*   ej  = (const int*)d_in[4];
    const int*   ek  = (const int*)d_in[5];
    const float* W1  = (const float*)d_in[6];
    const float* b1  = (const float*)d_in[7];
    const float* W2  = (const float*)d_in[8];
    const float* b2  = (const float*)d_in[9];
    const float* Ws1 = (const float*)d_in[10];
    const float* bs1 = (const float*)d_in[11];
    const float* Ws2 = (const float*)d_in[12];
    const float* bs2 = (const float*)d_in[13];
    float* out = (float*)d_out;
    const int nnz = in_sizes[2];

    char* ws = (char*)d_ws;
    float* x1    = (float*)ws;                             // [0, 2MB)
    int* deg     = (int*)(ws + (2 << 20));                 // 32 KB
    int* ovf_cnt = (int*)(ws + (2 << 20) + (32 << 10));    // 4 B
    int4* ovf    = (int4*)(ws + (2 << 20) + (64 << 10));   // 64 KB
    int* counts  = (int*)(ws + (4 << 20));                 // [4MB, 12MB)
    int* offs    = (int*)(ws + (12 << 20));                // [12MB, 20MB)
    int2* rec    = (int2*)(ws + (20 << 20));               // [20MB, 36MB)

    count_kernel<<<NB + BN / 4, 256, 0, stream>>>(x, W1, b1, W2, b2, Ws1, bs1, Ws2, bs2,
                                                  eb, ei, counts, x1, out, nnz);
    scan_kernel<<<NSEG / 256, 256, 0, stream>>>(counts, offs, deg, ovf_cnt);
    scatter_kernel<<<NB, 256, 0, stream>>>(eb, ei, ej, ek, offs, rec, ovf_cnt, ovf, nnz);
    gather_kernel<<<NSEG / 4, 256, 0, stream>>>((const f32x4*)Wv, (const f32x4*)x1,
                                                deg, rec, ovf_cnt, ovf, (f32x4*)out);
}

// Round 16
// 129.855 us; speedup vs baseline: 1.0955x; 1.0374x over previous
//
#include <hip/hip_runtime.h>

#define BN 8192      // B*N
#define NP 1024      // N
#define NF 64        // F_OUT
#define NSEG 8192
#define CAP 256      // bucket capacity; overflow handled exactly
#define NB 512       // counting blocks
#define EPB 2048     // edges per counting block
#define G 32         // block-rows per scan group
#define NG (NB / G)  // 16 groups
#define OVF_MAX 4096

typedef float f32x4 __attribute__((ext_vector_type(4)));

// K1: blocks [0,NB) build per-block seg histograms in LDS -> counts[b][*]
//     blocks [NB,..) dual MLP (wave per row, shfl broadcast)
__global__ __launch_bounds__(256) void count_kernel(
    const float* __restrict__ x,
    const float* __restrict__ W1, const float* __restrict__ b1,
    const float* __restrict__ W2, const float* __restrict__ b2,
    const float* __restrict__ Ws1, const float* __restrict__ bs1,
    const float* __restrict__ Ws2, const float* __restrict__ bs2,
    const int* __restrict__ eb, const int* __restrict__ ei,
    int* __restrict__ counts,
    float* __restrict__ x1, float* __restrict__ out, int nnz)
{
    __shared__ int hist[NSEG];
    if ((int)blockIdx.x < NB) {
        const int t = threadIdx.x;
        #pragma unroll
        for (int q = 0; q < 8; ++q)
            *(int4*)(hist + (q * 256 + t) * 4) = make_int4(0, 0, 0, 0);
        __syncthreads();
        const int base = blockIdx.x * EPB;
        #pragma unroll
        for (int q = 0; q < 2; ++q) {
            const int e0 = base + (q * 256 + t) * 4;
            if (e0 < nnz) {
                const int4 b4 = *(const int4*)(eb + e0);
                const int4 i4 = *(const int4*)(ei + e0);
                atomicAdd(&hist[b4.x * NP + i4.x], 1);
                atomicAdd(&hist[b4.y * NP + i4.y], 1);
                atomicAdd(&hist[b4.z * NP + i4.z], 1);
                atomicAdd(&hist[b4.w * NP + i4.w], 1);
            }
        }
        __syncthreads();
        int* row = counts + (size_t)blockIdx.x * NSEG;
        #pragma unroll
        for (int q = 0; q < 8; ++q) {
            const int idx = (q * 256 + t) * 4;
            *(int4*)(row + idx) = *(const int4*)(hist + idx);
        }
    } else {
        // dual MLP: one wave per row, shfl broadcasts, no barriers
        const int row = ((int)blockIdx.x - NB) * 4 + (threadIdx.x >> 6);
        const int t = threadIdx.x & 63;
        const float xv = x[(size_t)row * NF + t];
        float a1 = b1[t], a2 = bs1[t];
        #pragma unroll 8
        for (int c = 0; c < NF; ++c) {
            const float xc = __shfl(xv, c);
            a1 = fmaf(xc, W1[c * NF + t], a1);
            a2 = fmaf(xc, Ws1[c * NF + t], a2);
        }
        const float h1 = fmaxf(a1, 0.f), h2 = fmaxf(a2, 0.f);
        float o1 = b2[t], o2 = bs2[t];
        #pragma unroll 8
        for (int c = 0; c < NF; ++c) {
            o1 = fmaf(__shfl(h1, c), W2[c * NF + t], o1);
            o2 = fmaf(__shfl(h2, c), Ws2[c * NF + t], o2);
        }
        x1[(size_t)row * NF + t]  = fmaxf(o1, 0.f);
        out[(size_t)row * NF + t] = fmaxf(o2, 0.f);
    }
}

// K2a: per-(group,seg) sum of 32 block rows. 128K threads, coalesced.
__global__ __launch_bounds__(256) void scan_a_kernel(
    const int* __restrict__ counts, int* __restrict__ gsum)
{
    const int tid = blockIdx.x * 256 + threadIdx.x;   // 16*8192 threads
    const int g = tid >> 13, s = tid & (NSEG - 1);
    const int* col = counts + (size_t)g * G * NSEG + s;
    int sum = 0;
    #pragma unroll
    for (int i = 0; i < G; ++i) sum += col[(size_t)i * NSEG];
    gsum[g * NSEG + s] = sum;
}

// K2b: per-seg exclusive scan over the 16 group sums; writes deg.
__global__ __launch_bounds__(256) void scan_b_kernel(
    const int* __restrict__ gsum, int* __restrict__ gbase,
    int* __restrict__ deg, int* __restrict__ ovf_cnt)
{
    const int s = blockIdx.x * 256 + threadIdx.x;     // 8192 threads
    int run = 0;
    #pragma unroll
    for (int g = 0; g < NG; ++g) {
        gbase[g * NSEG + s] = run;
        run += gsum[g * NSEG + s];
    }
    deg[s] = run;
    if (s == 0) *ovf_cnt = 0;
}

// K2c: expand within each group -> offs[b][s]. 128K threads, coalesced.
__global__ __launch_bounds__(256) void scan_c_kernel(
    const int* __restrict__ counts, const int* __restrict__ gbase,
    int* __restrict__ offs)
{
    const int tid = blockIdx.x * 256 + threadIdx.x;
    const int g = tid >> 13, s = tid & (NSEG - 1);
    int run = gbase[g * NSEG + s];
    const int* col = counts + (size_t)g * G * NSEG + s;
    int* ocol = offs + (size_t)g * G * NSEG + s;
    #pragma unroll
    for (int i = 0; i < G; ++i) {
        ocol[(size_t)i * NSEG] = run;
        run += col[(size_t)i * NSEG];
    }
}

// K3: deterministic scatter. Block's cursor row lives in LDS (LDS atomics);
// global rec position = offs[b][seg] + local append index. No global atomics.
__global__ __launch_bounds__(256) void scatter_kernel(
    const int* __restrict__ eb, const int* __restrict__ ei,
    const int* __restrict__ ej, const int* __restrict__ ek,
    const int* __restrict__ offs,
    int2* __restrict__ rec, int* __restrict__ ovf_cnt, int4* __restrict__ ovf,
    int nnz)
{
    __shared__ int cur[NSEG];
    const int t = threadIdx.x;
    const int* row = offs + (size_t)blockIdx.x * NSEG;
    #pragma unroll
    for (int q = 0; q < 8; ++q) {
        const int idx = (q * 256 + t) * 4;
        *(int4*)(cur + idx) = *(const int4*)(row + idx);
    }
    __syncthreads();
    const int base = blockIdx.x * EPB;
    #pragma unroll
    for (int q = 0; q < 2; ++q) {
        const int e0 = base + (q * 256 + t) * 4;
        if (e0 < nnz) {
            const int4 b4 = *(const int4*)(eb + e0);
            const int4 i4 = *(const int4*)(ei + e0);
            const int4 j4 = *(const int4*)(ej + e0);
            const int4 k4 = *(const int4*)(ek + e0);
            const int segs[4] = {b4.x * NP + i4.x, b4.y * NP + i4.y,
                                 b4.z * NP + i4.z, b4.w * NP + i4.w};
            const int jks[4]  = {(j4.x << 10) | k4.x, (j4.y << 10) | k4.y,
                                 (j4.z << 10) | k4.z, (j4.w << 10) | k4.w};
            #pragma unroll
            for (int c = 0; c < 4; ++c) {
                const int pos = atomicAdd(&cur[segs[c]], 1);   // LDS atomic
                if (pos < CAP) {
                    rec[(size_t)segs[c] * CAP + pos] = make_int2(e0 + c, jks[c]);
                } else {
                    const int o = atomicAdd(ovf_cnt, 1);
                    if (o < OVF_MAX) ovf[o] = make_int4(segs[c], e0 + c, jks[c], 0);
                }
            }
        }
    }
}

// Wave-per-segment gather: 4 independent waves per block, NO barriers.
// (Byte-identical to round 13, nt Wv load restored.)
__global__ __launch_bounds__(256, 8) void gather_kernel(
    const f32x4* __restrict__ Wv4, const f32x4* __restrict__ x14,
    const int* __restrict__ deg, const int2* __restrict__ rec,
    const int* __restrict__ ovf_cnt, const int4* __restrict__ ovf,
    f32x4* __restrict__ out4)
{
    __shared__ int2 srec[4][CAP + 4];
    const int w    = threadIdx.x >> 6;
    const int lane = threadIdx.x & 63;
    const int seg  = blockIdx.x * 4 + w;
    const int b    = seg >> 10;
    const int dtrue = deg[seg];
    const int cnt  = min(dtrue, CAP);
    const int cnt4 = (cnt + 3) & ~3;

    for (int i = lane; i < cnt; i += 64)
        srec[w][i] = rec[(size_t)seg * CAP + i];
    if (lane < cnt4 - cnt)
        srec[w][cnt + lane] = make_int2(0, 0);

    const int sub = lane >> 4;
    const int c16 = lane & 15;
    const f32x4* __restrict__ x1b = x14 + ((size_t)b << 10) * 16;

    f32x4 acc = {0.f, 0.f, 0.f, 0.f};
    #pragma unroll 2
    for (int it = 0; it < cnt4; it += 4) {
        const int idx = it + sub;
        const float m = (idx < cnt) ? 1.f : 0.f;
        const int2 r = srec[w][idx];
        const int j = (r.y >> 10) & 1023, k = r.y & 1023;
        const f32x4 wv = __builtin_nontemporal_load(Wv4 + (size_t)(unsigned)r.x * 16 + c16);
        const f32x4 xj = x1b[j * 16 + c16];
        const f32x4 xk = x1b[k * 16 + c16];
        acc += (m * wv) * (xj * xk);
    }

    const int novf = min(ovf_cnt[0], OVF_MAX);
    if (novf > 0) {
        for (int o = 0; o < novf; ++o) {
            const int4 r = ovf[o];
            if (r.x == seg) {
                const float m = (sub == 0) ? 1.f : 0.f;
                const int j = (r.z >> 10) & 1023, k = r.z & 1023;
                const f32x4 wv = Wv4[(size_t)(unsigned)r.y * 16 + c16];
                acc += (m * wv) * (x1b[j * 16 + c16] * x1b[k * 16 + c16]);
            }
        }
    }

    #pragma unroll
    for (int mm = 16; mm < 64; mm <<= 1) {
        acc.x += __shfl_xor(acc.x, mm);
        acc.y += __shfl_xor(acc.y, mm);
        acc.z += __shfl_xor(acc.z, mm);
        acc.w += __shfl_xor(acc.w, mm);
    }

    if (sub == 0) {
        const float a = 1.0f / ((float)dtrue + 1e-10f);
        f32x4 o = out4[(size_t)seg * 16 + c16];
        out4[(size_t)seg * 16 + c16] = o + a * acc;
    }
}

extern "C" void kernel_launch(void* const* d_in, const int* in_sizes, int n_in,
                              void* d_out, int out_size, void* d_ws, size_t ws_size,
                              hipStream_t stream) {
    const float* x   = (const float*)d_in[0];
    const float* Wv  = (const float*)d_in[1];
    const int*   eb  = (const int*)d_in[2];
    const int*   ei  = (const int*)d_in[3];
    const int*   ej  = (const int*)d_in[4];
    const int*   ek  = (const int*)d_in[5];
    const float* W1  = (const float*)d_in[6];
    const float* b1  = (const float*)d_in[7];
    const float* W2  = (const float*)d_in[8];
    const float* b2  = (const float*)d_in[9];
    const float* Ws1 = (const float*)d_in[10];
    const float* bs1 = (const float*)d_in[11];
    const float* Ws2 = (const float*)d_in[12];
    const float* bs2 = (const float*)d_in[13];
    float* out = (float*)d_out;
    const int nnz = in_sizes[2];

    char* ws = (char*)d_ws;
    float* x1    = (float*)ws;                              // [0, 2MB)
    int* deg     = (int*)(ws + (2 << 20));                  // 32 KB
    int* ovf_cnt = (int*)(ws + (2 << 20) + (32 << 10));     // 4 B
    int4* ovf    = (int4*)(ws + (2 << 20) + (64 << 10));    // 64 KB
    int* gsum    = (int*)(ws + (2 << 20) + (128 << 10));    // 512 KB
    int* gbase   = (int*)(ws + (2 << 20) + (640 << 10));    // 512 KB
    int* counts  = (int*)(ws + (4 << 20));                  // [4MB, 20MB)
    int* offs    = (int*)(ws + (20 << 20));                 // [20MB, 36MB)
    int2* rec    = (int2*)(ws + (36 << 20));                // [36MB, 52MB)

    count_kernel<<<NB + BN / 4, 256, 0, stream>>>(x, W1, b1, W2, b2, Ws1, bs1, Ws2, bs2,
                                                  eb, ei, counts, x1, out, nnz);
    scan_a_kernel<<<NG * NSEG / 256, 256, 0, stream>>>(counts, gsum);
    scan_b_kernel<<<NSEG / 256, 256, 0, stream>>>(gsum, gbase, deg, ovf_cnt);
    scan_c_kernel<<<NG * NSEG / 256, 256, 0, stream>>>(counts, gbase, offs);
    scatter_kernel<<<NB, 256, 0, stream>>>(eb, ei, ej, ek, offs, rec, ovf_cnt, ovf, nnz);
    gather_kernel<<<NSEG / 4, 256, 0, stream>>>((const f32x4*)Wv, (const f32x4*)x1,
                                                deg, rec, ovf_cnt, ovf, (f32x4*)out);
}

// Round 17
// 116.470 us; speedup vs baseline: 1.2214x; 1.1149x over previous
//
#include <hip/hip_runtime.h>

#define BN 8192      // B*N
#define NP 1024      // N
#define NF 64        // F_OUT
#define NSEG 8192
#define NBIN 1024    // bins of 8 segments (bin = seg >> 3)
#define CAPBIN 1184  // Poisson(1024) + 5 sigma; overflow exact
#define OVF_MAX 4096
#define OVFS (1 << 30)   // sentinel: cursor values >= OVFS index the ovf list

typedef float f32x4 __attribute__((ext_vector_type(4)));

// K1: blocks [0,nsb): block-local counting sort of 8192 edges into dense global
//     per-bin strips (one global atomic per (block,bin); rec lines block-private).
//     blocks [nsb,..): dual MLP, 16 rows/block.
__global__ __launch_bounds__(1024) void prep_kernel(
    const float* __restrict__ x,
    const float* __restrict__ W1, const float* __restrict__ b1,
    const float* __restrict__ W2, const float* __restrict__ b2,
    const float* __restrict__ Ws1, const float* __restrict__ bs1,
    const float* __restrict__ Ws2, const float* __restrict__ bs2,
    const int* __restrict__ eb, const int* __restrict__ ei,
    const int* __restrict__ ej, const int* __restrict__ ek,
    int* __restrict__ gcur, int2* __restrict__ rec,
    int* __restrict__ ovf_cnt, int4* __restrict__ ovf,
    float* __restrict__ x1, float* __restrict__ out,
    int nnz, int nsb)
{
    if ((int)blockIdx.x < nsb) {
        __shared__ int hist[NBIN];
        __shared__ int cur[NBIN];
        const int t = threadIdx.x;
        hist[t] = 0;
        __syncthreads();

        int segs[8], jks[8];
        const int base = blockIdx.x * 8192;
        #pragma unroll
        for (int q = 0; q < 2; ++q) {
            const int e0 = base + (q * 1024 + t) * 4;
            if (e0 < nnz) {
                const int4 b4 = *(const int4*)(eb + e0);
                const int4 i4 = *(const int4*)(ei + e0);
                const int4 j4 = *(const int4*)(ej + e0);
                const int4 k4 = *(const int4*)(ek + e0);
                segs[q*4+0] = b4.x * NP + i4.x;  jks[q*4+0] = (j4.x << 10) | k4.x;
                segs[q*4+1] = b4.y * NP + i4.y;  jks[q*4+1] = (j4.y << 10) | k4.y;
                segs[q*4+2] = b4.z * NP + i4.z;  jks[q*4+2] = (j4.z << 10) | k4.z;
                segs[q*4+3] = b4.w * NP + i4.w;  jks[q*4+3] = (j4.w << 10) | k4.w;
                #pragma unroll
                for (int c = 0; c < 4; ++c)
                    atomicAdd(&hist[segs[q*4+c] >> 3], 1);
            } else {
                #pragma unroll
                for (int c = 0; c < 4; ++c) segs[q*4+c] = -1;
            }
        }
        __syncthreads();

        // reserve a dense range in bin t's strip (or divert whole chunk to ovf)
        {
            const int v = hist[t];
            int c = 0;
            if (v > 0) {
                const int r = atomicAdd(&gcur[t], v);
                if (r + v <= CAPBIN) {
                    c = t * CAPBIN + r;
                } else {
                    atomicSub(&gcur[t], v);            // keep gcur == stored count
                    c = OVFS + atomicAdd(ovf_cnt, v);
                }
            }
            cur[t] = c;
        }
        __syncthreads();

        #pragma unroll
        for (int q = 0; q < 2; ++q) {
            #pragma unroll
            for (int c = 0; c < 4; ++c) {
                const int idx = q * 4 + c;
                if (segs[idx] >= 0) {
                    const int e = base + (q * 1024 + t) * 4 + c;
                    const int seg = segs[idx];
                    const int p = atomicAdd(&cur[seg >> 3], 1);   // LDS atomic
                    if (p < OVFS) {
                        rec[p] = make_int2(e | ((seg & 7) << 20), jks[idx]);
                    } else {
                        const int o = p - OVFS;
                        if (o < OVF_MAX) ovf[o] = make_int4(seg, e, jks[idx], 0);
                    }
                }
            }
        }
    } else {
        // dual MLP: one wave per row, shfl broadcasts, no barriers
        const int row = ((int)blockIdx.x - nsb) * 16 + ((int)threadIdx.x >> 6);
        const int t = threadIdx.x & 63;
        const float xv = x[(size_t)row * NF + t];
        float a1 = b1[t], a2 = bs1[t];
        #pragma unroll 8
        for (int c = 0; c < NF; ++c) {
            const float xc = __shfl(xv, c);
            a1 = fmaf(xc, W1[c * NF + t], a1);
            a2 = fmaf(xc, Ws1[c * NF + t], a2);
        }
        const float h1 = fmaxf(a1, 0.f), h2 = fmaxf(a2, 0.f);
        float o1 = b2[t], o2 = bs2[t];
        #pragma unroll 8
        for (int c = 0; c < NF; ++c) {
            o1 = fmaf(__shfl(h1, c), W2[c * NF + t], o1);
            o2 = fmaf(__shfl(h2, c), Ws2[c * NF + t], o2);
        }
        x1[(size_t)row * NF + t]  = fmaxf(o1, 0.f);
        out[(size_t)row * NF + t] = fmaxf(o2, 0.f);
    }
}

// K2: block per bin (512 thr = 8 waves). Two passes over the bin's dense rec
// strip: LDS 8-counter hist (gives exact deg), prefix, scatter into sorted LDS;
// then the proven wave-per-seg gather inner loop (1 seg per wave).
__global__ __launch_bounds__(512, 8) void gather_kernel(
    const f32x4* __restrict__ Wv4, const f32x4* __restrict__ x14,
    const int* __restrict__ gcur, const int2* __restrict__ rec,
    const int* __restrict__ ovf_cnt, const int4* __restrict__ ovf,
    f32x4* __restrict__ out4)
{
    __shared__ int2 srt[CAPBIN];
    __shared__ int hist[8], cur2[8], base2[8];
    const int bin = blockIdx.x;
    const int t = threadIdx.x;
    const int cnt = gcur[bin];                     // <= CAPBIN by construction
    if (t < 8) hist[t] = 0;
    __syncthreads();

    const int2* strip = rec + (size_t)bin * CAPBIN;
    #pragma unroll
    for (int i = 0; i < 3; ++i) {                  // 3*512 >= CAPBIN
        const int idx = i * 512 + t;
        if (idx < cnt) atomicAdd(&hist[(strip[idx].x >> 20) & 7], 1);
    }
    __syncthreads();
    if (t < 8) {
        int bsum = 0;
        for (int s = 0; s < t; ++s) bsum += hist[s];
        base2[t] = bsum; cur2[t] = bsum;
    }
    __syncthreads();
    #pragma unroll
    for (int i = 0; i < 3; ++i) {                  // L2-hot second pass
        const int idx = i * 512 + t;
        if (idx < cnt) {
            const int2 r = strip[idx];
            srt[atomicAdd(&cur2[(r.x >> 20) & 7], 1)] = r;
        }
    }
    __syncthreads();

    const int w    = t >> 6;                        // wave = local seg 0..7
    const int lane = t & 63;
    const int sub  = lane >> 4;
    const int c16  = lane & 15;
    const int seg  = bin * 8 + w;
    const int b    = seg >> 10;
    const f32x4* __restrict__ x1b = x14 + ((size_t)b << 10) * 16;
    const int cs = hist[w], bs = base2[w];
    int dtrue = cs;

    f32x4 acc = {0.f, 0.f, 0.f, 0.f};
    #pragma unroll 2
    for (int it = 0; it < cs; it += 4) {
        int idx = it + sub;
        const float m = (idx < cs) ? 1.f : 0.f;
        idx = min(idx, cs - 1);                     // cs >= 1 inside loop
        const int2 r = srt[bs + idx];
        const int e = r.x & 0xFFFFF;
        const int j = (r.y >> 10) & 1023, k = r.y & 1023;
        const f32x4 wv = __builtin_nontemporal_load(Wv4 + (size_t)e * 16 + c16);
        const f32x4 xj = x1b[j * 16 + c16];
        const f32x4 xk = x1b[k * 16 + c16];
        acc += (m * wv) * (xj * xk);
    }

    // exact overflow path (expected empty)
    const int novf = min(ovf_cnt[0], OVF_MAX);
    if (novf > 0) {
        for (int o = 0; o < novf; ++o) {
            const int4 r = ovf[o];
            if (r.x == seg) {
                ++dtrue;
                const float m = (sub == 0) ? 1.f : 0.f;
                const int j = (r.z >> 10) & 1023, k = r.z & 1023;
                const f32x4 wv = Wv4[(size_t)(unsigned)r.y * 16 + c16];
                acc += (m * wv) * (x1b[j * 16 + c16] * x1b[k * 16 + c16]);
            }
        }
    }

    #pragma unroll
    for (int mm = 16; mm < 64; mm <<= 1) {
        acc.x += __shfl_xor(acc.x, mm);
        acc.y += __shfl_xor(acc.y, mm);
        acc.z += __shfl_xor(acc.z, mm);
        acc.w += __shfl_xor(acc.w, mm);
    }

    if (sub == 0) {
        const float a = 1.0f / ((float)dtrue + 1e-10f);
        f32x4 o = out4[(size_t)seg * 16 + c16];
        out4[(size_t)seg * 16 + c16] = o + a * acc;
    }
}

extern "C" void kernel_launch(void* const* d_in, const int* in_sizes, int n_in,
                              void* d_out, int out_size, void* d_ws, size_t ws_size,
                              hipStream_t stream) {
    const float* x   = (const float*)d_in[0];
    const float* Wv  = (const float*)d_in[1];
    const int*   eb  = (const int*)d_in[2];
    const int*   ei  = (const int*)d_in[3];
    const int*   ej  = (const int*)d_in[4];
    const int*   ek  = (const int*)d_in[5];
    const float* W1  = (const float*)d_in[6];
    const float* b1  = (const float*)d_in[7];
    const float* W2  = (const float*)d_in[8];
    const float* b2  = (const float*)d_in[9];
    const float* Ws1 = (const float*)d_in[10];
    const float* bs1 = (const float*)d_in[11];
    const float* Ws2 = (const float*)d_in[12];
    const float* bs2 = (const float*)d_in[13];
    float* out = (float*)d_out;
    const int nnz = in_sizes[2];

    char* ws = (char*)d_ws;
    float* x1    = (float*)ws;                             // [0, 2MB)
    int* gcur    = (int*)(ws + (2 << 20));                 // 4 KB (NBIN ints)
    int* ovf_cnt = gcur + NBIN;                            // 4 B (contiguous)
    int4* ovf    = (int4*)(ws + (2 << 20) + (64 << 10));   // 64 KB
    int2* rec    = (int2*)(ws + (4 << 20));                // 1024*1184*8 = 9.7 MB

    const int nsb = (nnz + 8191) / 8192;   // 128 sort blocks (1024 thr x 8 edges)
    const int nmlp = BN / 16;              // 512 MLP blocks (16 waves x 1 row)

    (void)hipMemsetAsync(gcur, 0, (NBIN + 1) * sizeof(int), stream);
    prep_kernel<<<nsb + nmlp, 1024, 0, stream>>>(x, W1, b1, W2, b2, Ws1, bs1, Ws2, bs2,
                                                 eb, ei, ej, ek, gcur, rec, ovf_cnt, ovf,
                                                 x1, out, nnz, nsb);
    gather_kernel<<<NBIN, 512, 0, stream>>>((const f32x4*)Wv, (const f32x4*)x1,
                                            gcur, rec, ovf_cnt, ovf, (f32x4*)out);
}